// Round 1
// baseline (8868.799 us; speedup 1.0000x reference)
//
#include <hip/hip_runtime.h>
#include <hip/hip_bf16.h>
#include <math.h>

#define BB 1024
#define TT 64
#define OBSN 64
#define ACTN 8
#define STOCHN 32
#define DETERN 512
#define HIDN 512
#define G3N 1536
#define CATPI 40
#define OUTC 672
#define LNEPS 1e-3f
#define MINSTD 0.1f
#define UPDBIAS -1.0f

__device__ __forceinline__ float sigmoidf_(float x) { return 1.f / (1.f + expf(-x)); }
__device__ __forceinline__ float siluf_(float x) { return x / (1.f + expf(-x)); }
__device__ __forceinline__ float softplusf_(float x) { return (x > 20.f) ? x : log1pf(expf(x)); }

// Block-wide reduction of NV float accumulators. red must hold (nwaves+1)*NV floats.
template <int NV>
__device__ __forceinline__ void breduce(float* v, float* red, int nwaves) {
    __syncthreads();  // protect red from previous use
#pragma unroll
    for (int off = 32; off > 0; off >>= 1)
#pragma unroll
        for (int q = 0; q < NV; ++q) v[q] += __shfl_down(v[q], off);
    int lane = threadIdx.x & 63, w = threadIdx.x >> 6;
    if (lane == 0)
        for (int q = 0; q < NV; ++q) red[w * NV + q] = v[q];
    __syncthreads();
    if ((int)threadIdx.x < NV) {
        float s = 0.f;
        for (int ww = 0; ww < nwaves; ++ww) s += red[ww * NV + threadIdx.x];
        red[nwaves * NV + threadIdx.x] = s;
    }
    __syncthreads();
#pragma unroll
    for (int q = 0; q < NV; ++q) v[q] = red[nwaves * NV + q];
}

// ---- once: d_init = tanh(init_deter); s_init = prior mean at d_init ----
__global__ __launch_bounds__(512) void k_init(const float* __restrict__ init_deter,
                                              const float* __restrict__ W_po, const float* __restrict__ g_po,
                                              const float* __restrict__ b_po, const float* __restrict__ W_ps,
                                              const float* __restrict__ b_ps, float* __restrict__ dinit,
                                              float* __restrict__ sinit) {
    __shared__ float d_s[512], h_s[512], red[40];
    int tid = threadIdx.x;
    float dv = tanhf(init_deter[tid]);
    d_s[tid] = dv;
    dinit[tid] = dv;
    __syncthreads();
    float acc = 0.f;
    for (int k = 0; k < 512; ++k) acc += d_s[k] * W_po[k * 512 + tid];
    float v[2] = {acc, acc * acc};
    breduce<2>(v, red, 8);
    float m = v[0] / 512.f, va = v[1] / 512.f - m * m, iv = rsqrtf(va + LNEPS);
    h_s[tid] = siluf_((acc - m) * iv * g_po[tid] + b_po[tid]);
    __syncthreads();
    if (tid < 32) {
        float s = b_ps[tid];
        for (int k = 0; k < 512; ++k) s += h_s[k] * W_ps[k * 64 + tid];
        sinit[tid] = s;
    }
}

// ---- t=0 only: mask state, x = silu(LN(cat(stoch,act) @ W_pi)) ----
__global__ __launch_bounds__(256) void k_prior_x(int t, const int* __restrict__ isf,
                                                 const float* __restrict__ action, const float* __restrict__ stoch,
                                                 const float* __restrict__ sinit, const float* __restrict__ dinit,
                                                 float* __restrict__ deter, const float* __restrict__ W_pi,
                                                 const float* __restrict__ g_pi, const float* __restrict__ b_pi,
                                                 float* __restrict__ xout) {
    int b = blockIdx.x, tid = threadIdx.x;
    __shared__ float a_s[CATPI];
    __shared__ float red[24];
    int first = isf[b * TT + t] > 0;
    if (tid < CATPI) {
        float v;
        if (tid < STOCHN)
            v = (t == 0 || first) ? sinit[tid] : stoch[b * STOCHN + tid];
        else
            v = first ? 0.f : action[((size_t)b * TT + t) * ACTN + (tid - STOCHN)];
        a_s[tid] = v;
    }
    for (int j = tid; j < DETERN; j += 256) {
        float dv = (t == 0 || first) ? dinit[j] : deter[(size_t)b * DETERN + j];
        deter[(size_t)b * DETERN + j] = dv;
    }
    __syncthreads();
    float o[2];
    float vs = 0.f, vq = 0.f;
#pragma unroll
    for (int s = 0; s < 2; ++s) {
        int j = tid + s * 256;
        float acc = 0.f;
        for (int k = 0; k < CATPI; ++k) acc += a_s[k] * W_pi[k * 512 + j];
        o[s] = acc;
        vs += acc;
        vq += acc * acc;
    }
    float v2[2] = {vs, vq};
    breduce<2>(v2, red, 4);
    float m = v2[0] / 512.f, va = v2[1] / 512.f - m * m, iv = rsqrtf(va + LNEPS);
#pragma unroll
    for (int s = 0; s < 2; ++s) {
        int j = tid + s * 256;
        xout[(size_t)b * 512 + j] = siluf_((o[s] - m) * iv * g_pi[j] + b_pi[j]);
    }
}

// ---- GRU GEMM: gates_raw = cat(x, deter) @ W_gru   (M=1024, K=1024, N=1536) ----
__global__ __launch_bounds__(256) void k_gemm_gru(const float* __restrict__ x, const float* __restrict__ deter,
                                                  const float* __restrict__ Wg, float* __restrict__ gates) {
    __shared__ float As[16][64];
    __shared__ float Bs[16][64];
    int bm0 = (blockIdx.x % 16) * 64;
    int bn0 = (blockIdx.x / 16) * 64;
    int tid = threadIdx.x;
    int tx = tid & 15, ty = tid >> 4;
    float c[4][4] = {};
    int arow = tid >> 2;
    int akq = (tid & 3) * 4;
    for (int k0 = 0; k0 < 1024; k0 += 16) {
        const float* asrc = (k0 < HIDN) ? (x + (size_t)(bm0 + arow) * HIDN + k0 + akq)
                                        : (deter + (size_t)(bm0 + arow) * DETERN + (k0 - HIDN) + akq);
        float4 av = *(const float4*)asrc;
        As[akq + 0][arow] = av.x;
        As[akq + 1][arow] = av.y;
        As[akq + 2][arow] = av.z;
        As[akq + 3][arow] = av.w;
#pragma unroll
        for (int q = 0; q < 4; ++q) {
            int idx = tid + q * 256;
            int kk = idx >> 6, n = idx & 63;
            Bs[kk][n] = Wg[(size_t)(k0 + kk) * G3N + bn0 + n];
        }
        __syncthreads();
#pragma unroll
        for (int kk = 0; kk < 16; ++kk) {
            float4 a4 = *(const float4*)&As[kk][ty * 4];
            float4 b4 = *(const float4*)&Bs[kk][tx * 4];
            float ar[4] = {a4.x, a4.y, a4.z, a4.w};
            float br[4] = {b4.x, b4.y, b4.z, b4.w};
#pragma unroll
            for (int i = 0; i < 4; ++i)
#pragma unroll
                for (int j = 0; j < 4; ++j) c[i][j] += ar[i] * br[j];
        }
        __syncthreads();
    }
#pragma unroll
    for (int i = 0; i < 4; ++i)
#pragma unroll
        for (int j = 0; j < 4; ++j)
            gates[(size_t)(bm0 + ty * 4 + i) * G3N + bn0 + tx * 4 + j] = c[i][j];
}

// ---- LN over gates + GRU update -> deter_n (also writes deter slice of out) ----
__global__ __launch_bounds__(256) void k_gru_update(int t, const float* __restrict__ gates,
                                                    const float* __restrict__ g_gru, const float* __restrict__ b_gru,
                                                    float* __restrict__ deter, float* __restrict__ out) {
    int b = blockIdx.x, tid = threadIdx.x;
    __shared__ float red[24];
    const float* grow = gates + (size_t)b * G3N;
    float g[6];
    float s = 0.f, sq = 0.f;
#pragma unroll
    for (int q = 0; q < 6; ++q) {
        g[q] = grow[tid + q * 256];
        s += g[q];
        sq += g[q] * g[q];
    }
    float v[2] = {s, sq};
    breduce<2>(v, red, 4);
    float m = v[0] / 1536.f, va = v[1] / 1536.f - m * m, iv = rsqrtf(va + LNEPS);
    size_t base = ((size_t)b * TT + t) * OUTC + 160;
#pragma unroll
    for (int s2 = 0; s2 < 2; ++s2) {
        int j = tid + s2 * 256;
        float rv = sigmoidf_((g[s2] - m) * iv * g_gru[j] + b_gru[j]);
        float cv = (g[2 + s2] - m) * iv * g_gru[512 + j] + b_gru[512 + j];
        float uv = sigmoidf_((g[4 + s2] - m) * iv * g_gru[1024 + j] + b_gru[1024 + j] + UPDBIAS);
        float cand = siluf_(rv * cv);
        float dp = deter[(size_t)b * DETERN + j];
        float dn = uv * cand + (1.f - uv) * dp;
        deter[(size_t)b * DETERN + j] = dn;
        out[base + j] = dn;
    }
}

// ---- hp_raw = deter_n @ W_po ; hq_raw = cat(deter_n, obs_t) @ W_pn  (N halves) ----
__global__ __launch_bounds__(256) void k_gemm_h(int t, const float* __restrict__ deter, const float* __restrict__ obs,
                                                const float* __restrict__ W_po, const float* __restrict__ W_pn,
                                                float* __restrict__ hbuf) {
    __shared__ float As[16][64];
    __shared__ float Bs[16][64];
    int bm0 = (blockIdx.x % 16) * 64;
    int bn0 = (blockIdx.x / 16) * 64;
    int tid = threadIdx.x;
    int tx = tid & 15, ty = tid >> 4;
    int second = bn0 >= 512;
    const float* W = second ? W_pn : W_po;
    int ncol0 = second ? (bn0 - 512) : bn0;
    int K = second ? 576 : 512;
    float c[4][4] = {};
    int arow = tid >> 2;
    int akq = (tid & 3) * 4;
    for (int k0 = 0; k0 < K; k0 += 16) {
        const float* asrc;
        if (k0 < 512)
            asrc = deter + (size_t)(bm0 + arow) * DETERN + k0 + akq;
        else
            asrc = obs + ((size_t)(bm0 + arow) * TT + t) * OBSN + (k0 - 512) + akq;
        float4 av = *(const float4*)asrc;
        As[akq + 0][arow] = av.x;
        As[akq + 1][arow] = av.y;
        As[akq + 2][arow] = av.z;
        As[akq + 3][arow] = av.w;
#pragma unroll
        for (int q = 0; q < 4; ++q) {
            int idx = tid + q * 256;
            int kk = idx >> 6, n = idx & 63;
            Bs[kk][n] = W[(size_t)(k0 + kk) * 512 + ncol0 + n];
        }
        __syncthreads();
#pragma unroll
        for (int kk = 0; kk < 16; ++kk) {
            float4 a4 = *(const float4*)&As[kk][ty * 4];
            float4 b4 = *(const float4*)&Bs[kk][tx * 4];
            float ar[4] = {a4.x, a4.y, a4.z, a4.w};
            float br[4] = {b4.x, b4.y, b4.z, b4.w};
#pragma unroll
            for (int i = 0; i < 4; ++i)
#pragma unroll
                for (int j = 0; j < 4; ++j) c[i][j] += ar[i] * br[j];
        }
        __syncthreads();
    }
#pragma unroll
    for (int i = 0; i < 4; ++i)
#pragma unroll
        for (int j = 0; j < 4; ++j)
            hbuf[(size_t)(bm0 + ty * 4 + i) * 1024 + bn0 + tx * 4 + j] = c[i][j];
}

// ---- LN+silu on hp/hq, stats GEMMs, write outputs, update stoch, fused next-step prior_in ----
__global__ __launch_bounds__(256) void k_stats(int t, const float* __restrict__ hbuf,
                                               const float* __restrict__ g_po, const float* __restrict__ b_po,
                                               const float* __restrict__ g_pn, const float* __restrict__ b_pn,
                                               const float* __restrict__ W_ps, const float* __restrict__ b_ps,
                                               const float* __restrict__ W_pt, const float* __restrict__ b_pt,
                                               const int* __restrict__ isf, const float* __restrict__ action,
                                               const float* __restrict__ sinit, const float* __restrict__ dinit,
                                               float* __restrict__ deter, float* __restrict__ stoch,
                                               const float* __restrict__ W_pi, const float* __restrict__ g_pi,
                                               const float* __restrict__ b_pi, float* __restrict__ xout,
                                               float* __restrict__ out) {
    int b = blockIdx.x, tid = threadIdx.x;
    __shared__ float hp_s[512], hq_s[512], ps_s[64], qs_s[64], a_s[CATPI], red[24];
    const float* hrow = hbuf + (size_t)b * 1024;
    float p0 = hrow[tid], p1 = hrow[tid + 256];
    float q0 = hrow[512 + tid], q1 = hrow[512 + tid + 256];
    float v[4] = {p0 + p1, p0 * p0 + p1 * p1, q0 + q1, q0 * q0 + q1 * q1};
    breduce<4>(v, red, 4);
    float mp = v[0] / 512.f, vp = v[1] / 512.f - mp * mp, ip = rsqrtf(vp + LNEPS);
    float mq = v[2] / 512.f, vq = v[3] / 512.f - mq * mq, iq = rsqrtf(vq + LNEPS);
    hp_s[tid] = siluf_((p0 - mp) * ip * g_po[tid] + b_po[tid]);
    hp_s[tid + 256] = siluf_((p1 - mp) * ip * g_po[tid + 256] + b_po[tid + 256]);
    hq_s[tid] = siluf_((q0 - mq) * iq * g_pn[tid] + b_pn[tid]);
    hq_s[tid + 256] = siluf_((q1 - mq) * iq * g_pn[tid + 256] + b_pn[tid + 256]);
    __syncthreads();
    if (tid < 64) {
        float acc = b_ps[tid];
        for (int k = 0; k < 512; ++k) acc += hp_s[k] * W_ps[k * 64 + tid];
        ps_s[tid] = acc;
    } else if (tid < 128) {
        int j = tid - 64;
        float acc = b_pt[j];
        for (int k = 0; k < 512; ++k) acc += hq_s[k] * W_pt[k * 64 + j];
        qs_s[j] = acc;
    }
    __syncthreads();
    size_t base = ((size_t)b * TT + t) * OUTC;
    if (tid < 32) {
        float qm = qs_s[tid], pm = ps_s[tid];
        out[base + tid] = qm;
        out[base + 32 + tid] = softplusf_(qs_s[32 + tid]) + MINSTD;
        out[base + 64 + tid] = qm;
        out[base + 96 + tid] = pm;
        out[base + 128 + tid] = softplusf_(ps_s[32 + tid]) + MINSTD;
        stoch[b * STOCHN + tid] = qm;
    }
    if (t + 1 < TT) {
        int first1 = isf[b * TT + t + 1] > 0;
        if (tid < CATPI) {
            float av;
            if (tid < STOCHN)
                av = first1 ? sinit[tid] : qs_s[tid];
            else
                av = first1 ? 0.f : action[((size_t)b * TT + t + 1) * ACTN + (tid - STOCHN)];
            a_s[tid] = av;
        }
        if (first1) {
            for (int j = tid; j < 512; j += 256) deter[(size_t)b * DETERN + j] = dinit[j];
        }
        __syncthreads();
        float o0 = 0.f, o1 = 0.f;
        for (int k = 0; k < CATPI; ++k) {
            float ak = a_s[k];
            o0 += ak * W_pi[k * 512 + tid];
            o1 += ak * W_pi[k * 512 + tid + 256];
        }
        float v2[2] = {o0 + o1, o0 * o0 + o1 * o1};
        breduce<2>(v2, red, 4);
        float m = v2[0] / 512.f, va = v2[1] / 512.f - m * m, iv = rsqrtf(va + LNEPS);
        xout[(size_t)b * 512 + tid] = siluf_((o0 - m) * iv * g_pi[tid] + b_pi[tid]);
        xout[(size_t)b * 512 + tid + 256] = siluf_((o1 - m) * iv * g_pi[tid + 256] + b_pi[tid + 256]);
    }
}

extern "C" void kernel_launch(void* const* d_in, const int* in_sizes, int n_in, void* d_out, int out_size, void* d_ws,
                              size_t ws_size, hipStream_t stream) {
    const float* obs = (const float*)d_in[0];
    const float* action = (const float*)d_in[1];
    const int* is_first = (const int*)d_in[2];
    const float* W_pi = (const float*)d_in[3];
    const float* g_pi = (const float*)d_in[4];
    const float* b_pi = (const float*)d_in[5];
    const float* W_gru = (const float*)d_in[6];
    const float* g_gru = (const float*)d_in[7];
    const float* b_gru = (const float*)d_in[8];
    const float* W_po = (const float*)d_in[9];
    const float* g_po = (const float*)d_in[10];
    const float* b_po = (const float*)d_in[11];
    const float* W_ps = (const float*)d_in[12];
    const float* b_ps = (const float*)d_in[13];
    const float* W_pn = (const float*)d_in[14];
    const float* g_pn = (const float*)d_in[15];
    const float* b_pn = (const float*)d_in[16];
    const float* W_pt = (const float*)d_in[17];
    const float* b_pt = (const float*)d_in[18];
    const float* init_deter = (const float*)d_in[19];
    float* out = (float*)d_out;
    float* ws = (float*)d_ws;

    float* deter = ws;                       // B*512
    float* stoch = deter + (size_t)BB * 512; // B*32
    float* xbuf = stoch + (size_t)BB * 32;   // B*512
    float* gates = xbuf + (size_t)BB * 512;  // B*1536
    float* hbuf = gates + (size_t)BB * 1536; // B*1024
    float* dinit = hbuf + (size_t)BB * 1024; // 512
    float* sinit = dinit + 512;              // 32

    k_init<<<1, 512, 0, stream>>>(init_deter, W_po, g_po, b_po, W_ps, b_ps, dinit, sinit);
    k_prior_x<<<BB, 256, 0, stream>>>(0, is_first, action, stoch, sinit, dinit, deter, W_pi, g_pi, b_pi, xbuf);
    for (int t = 0; t < TT; ++t) {
        k_gemm_gru<<<384, 256, 0, stream>>>(xbuf, deter, W_gru, gates);
        k_gru_update<<<BB, 256, 0, stream>>>(t, gates, g_gru, b_gru, deter, out);
        k_gemm_h<<<256, 256, 0, stream>>>(t, deter, obs, W_po, W_pn, hbuf);
        k_stats<<<BB, 256, 0, stream>>>(t, hbuf, g_po, b_po, g_pn, b_pn, W_ps, b_ps, W_pt, b_pt, is_first, action,
                                        sinit, dinit, deter, stoch, W_pi, g_pi, b_pi, xbuf, out);
    }
}

// Round 2
// 3635.867 us; speedup vs baseline: 2.4393x; 2.4393x over previous
//
#include <hip/hip_runtime.h>
#include <hip/hip_bf16.h>
#include <math.h>

#define BB 1024
#define TT 64
#define OBSN 64
#define ACTN 8
#define STOCHN 32
#define DETERN 512
#define HIDN 512
#define G3N 1536
#define CATPI 40
#define OUTC 672
#define LNEPS 1e-3f
#define MINSTD 0.1f
#define UPDBIAS -1.0f

typedef __attribute__((ext_vector_type(8))) short short8;
typedef __attribute__((ext_vector_type(4))) float f32x4;

__device__ __forceinline__ float sigmoidf_(float x) { return 1.f / (1.f + expf(-x)); }
__device__ __forceinline__ float siluf_(float x) { return x / (1.f + expf(-x)); }
__device__ __forceinline__ float softplusf_(float x) { return (x > 20.f) ? x : log1pf(expf(x)); }

__device__ __forceinline__ void gload_lds16(const void* g, void* l) {
    __builtin_amdgcn_global_load_lds((const __attribute__((address_space(1))) void*)g,
                                     (__attribute__((address_space(3))) void*)l, 16, 0, 0);
}

// Block-wide reduction of NV float accumulators. red must hold (nwaves+1)*NV floats.
template <int NV>
__device__ __forceinline__ void breduce(float* v, float* red, int nwaves) {
    __syncthreads();
#pragma unroll
    for (int off = 32; off > 0; off >>= 1)
#pragma unroll
        for (int q = 0; q < NV; ++q) v[q] += __shfl_down(v[q], off);
    int lane = threadIdx.x & 63, w = threadIdx.x >> 6;
    if (lane == 0)
        for (int q = 0; q < NV; ++q) red[w * NV + q] = v[q];
    __syncthreads();
    if ((int)threadIdx.x < NV) {
        float s = 0.f;
        for (int ww = 0; ww < nwaves; ++ww) s += red[ww * NV + threadIdx.x];
        red[nwaves * NV + threadIdx.x] = s;
    }
    __syncthreads();
#pragma unroll
    for (int q = 0; q < NV; ++q) v[q] = red[nwaves * NV + q];
}

// ---- transpose + fp32->bf16: dst[N][K] = src[K][N] ----
__global__ __launch_bounds__(256) void k_transpose_bf(const float* __restrict__ src,
                                                      __hip_bfloat16* __restrict__ dst, int K, int N) {
    __shared__ float t[32][33];
    int nTK = K >> 5;
    int k0 = (blockIdx.x % nTK) * 32;
    int n0 = (blockIdx.x / nTK) * 32;
    int tx = threadIdx.x & 31, ty = threadIdx.x >> 5;
#pragma unroll
    for (int i = 0; i < 4; ++i) t[ty + i * 8][tx] = src[(size_t)(k0 + ty + i * 8) * N + n0 + tx];
    __syncthreads();
#pragma unroll
    for (int i = 0; i < 4; ++i)
        dst[(size_t)(n0 + ty + i * 8) * K + k0 + tx] = __float2bfloat16(t[tx][ty + i * 8]);
}

// ---- fp32 -> bf16 elementwise ----
__global__ __launch_bounds__(256) void k_cvt_bf(const float* __restrict__ src, __hip_bfloat16* __restrict__ dst,
                                                int n) {
    for (int i = blockIdx.x * 256 + threadIdx.x; i < n; i += gridDim.x * 256) dst[i] = __float2bfloat16(src[i]);
}

// ==== MFMA GEMM core: C[M x N] = concat(A0,A1)[M x K] @ Wt^T (Wt is [N][K] bf16 row-major) ====
// BM=64, BN=128, BK=64, 256 threads = 4 waves in 2x2; each wave 32x64 (2x4 frags of 16x16).
// LDS layout: A [64 rows][8 slots of 16B], slot XOR (row&7); B [128 rows][8 slots], same swizzle.
__device__ __forceinline__ void gemm_core(const __hip_bfloat16* __restrict__ A0, int ld0, int K0,
                                          const __hip_bfloat16* __restrict__ A1, int ld1,
                                          const __hip_bfloat16* __restrict__ Wt, int ldW, int wn0,
                                          float* __restrict__ C, int ldc, int cm0, int cn0, int nK, char* smem) {
    char* smA = smem;          // 8 KB
    char* smB = smem + 8192;   // 16 KB
    int tid = threadIdx.x;
    int lane = tid & 63, wid = tid >> 6;
    int wr = wid >> 1, wc = wid & 1;
    int rseg = lane >> 3;  // row within 8-row segment
    int slot = lane & 7;   // 16B slot within row
    f32x4 acc[2][4] = {};
    for (int kt = 0; kt < nK; ++kt) {
        int k0 = kt * 64;
        const __hip_bfloat16* Ab;
        int ldA, kloc;
        if (k0 < K0) { Ab = A0; ldA = ld0; kloc = k0; }
        else { Ab = A1; ldA = ld1; kloc = k0 - K0; }
        // stage A: 8 segments of 8 rows (2 per wave)
#pragma unroll
        for (int i = 0; i < 2; ++i) {
            int seg = wid * 2 + i;
            int row = seg * 8 + rseg;
            int kk = kloc + ((slot ^ (row & 7)) << 3);
            gload_lds16(Ab + (size_t)(cm0 + row) * ldA + kk, smA + seg * 1024);
        }
        // stage B: 16 segments (4 per wave)
#pragma unroll
        for (int i = 0; i < 4; ++i) {
            int seg = wid * 4 + i;
            int row = seg * 8 + rseg;
            int kk = k0 + ((slot ^ (row & 7)) << 3);
            gload_lds16(Wt + (size_t)(wn0 + row) * ldW + kk, smB + seg * 1024);
        }
        __syncthreads();  // drains vmcnt: staged data visible
#pragma unroll
        for (int ks = 0; ks < 2; ++ks) {
            short8 af[2], bfr[4];
            int kslot = ks * 4 + (lane >> 4);
#pragma unroll
            for (int m = 0; m < 2; ++m) {
                int row = wr * 32 + m * 16 + (lane & 15);
                af[m] = *(const short8*)(smA + row * 128 + ((kslot ^ (row & 7)) << 4));
            }
#pragma unroll
            for (int n = 0; n < 4; ++n) {
                int row = wc * 64 + n * 16 + (lane & 15);
                bfr[n] = *(const short8*)(smB + row * 128 + ((kslot ^ (row & 7)) << 4));
            }
#pragma unroll
            for (int m = 0; m < 2; ++m)
#pragma unroll
                for (int n = 0; n < 4; ++n)
                    acc[m][n] = __builtin_amdgcn_mfma_f32_16x16x32_bf16(af[m], bfr[n], acc[m][n], 0, 0, 0);
        }
        __syncthreads();  // reads done before next stage overwrites
    }
    int r0 = cm0 + wr * 32 + (lane >> 4) * 4;
    int c0 = cn0 + wc * 64 + (lane & 15);
#pragma unroll
    for (int m = 0; m < 2; ++m)
#pragma unroll
        for (int n = 0; n < 4; ++n)
#pragma unroll
            for (int i = 0; i < 4; ++i)
                C[(size_t)(r0 + m * 16 + i) * ldc + c0 + n * 16] = acc[m][n][i];
}

// gates = cat(x, deter) @ W_gru : M=1024 K=1024 N=1536
__global__ __launch_bounds__(256) void k_gemm_gru(const __hip_bfloat16* __restrict__ xbf,
                                                  const __hip_bfloat16* __restrict__ dbf,
                                                  const __hip_bfloat16* __restrict__ WgT,
                                                  float* __restrict__ gates) {
    __shared__ __align__(16) char smem[24576];
    int bm = blockIdx.x & 15, bn = blockIdx.x >> 4;
    gemm_core(xbf, HIDN, 512, dbf, DETERN, WgT, 1024, bn * 128, gates, G3N, bm * 64, bn * 128, 16, smem);
}

// hbuf[:, :512] = deter @ W_po ; hbuf[:, 512:] = cat(deter, obs_t) @ W_pn
__global__ __launch_bounds__(256) void k_gemm_h(int t, const __hip_bfloat16* __restrict__ dbf,
                                                const __hip_bfloat16* __restrict__ obsbf,
                                                const __hip_bfloat16* __restrict__ WpoT,
                                                const __hip_bfloat16* __restrict__ WpnT, float* __restrict__ hbuf) {
    __shared__ __align__(16) char smem[24576];
    int bm = blockIdx.x & 15, bn = blockIdx.x >> 4;
    if (bn < 4)
        gemm_core(dbf, DETERN, 512, dbf, DETERN, WpoT, 512, bn * 128, hbuf, 1024, bm * 64, bn * 128, 8, smem);
    else
        gemm_core(dbf, DETERN, 512, obsbf + t * OBSN, TT * OBSN, WpnT, 576, (bn - 4) * 128, hbuf, 1024, bm * 64,
                  bn * 128, 9, smem);
}

// ---- once: d_init = tanh(init_deter); s_init = prior mean at d_init ----
__global__ __launch_bounds__(512) void k_init(const float* __restrict__ init_deter, const float* __restrict__ W_po,
                                              const float* __restrict__ g_po, const float* __restrict__ b_po,
                                              const float* __restrict__ W_ps, const float* __restrict__ b_ps,
                                              float* __restrict__ dinit, float* __restrict__ sinit) {
    __shared__ float d_s[512], h_s[512], red[40];
    int tid = threadIdx.x;
    float dv = tanhf(init_deter[tid]);
    d_s[tid] = dv;
    dinit[tid] = dv;
    __syncthreads();
    float acc = 0.f;
    for (int k = 0; k < 512; ++k) acc += d_s[k] * W_po[k * 512 + tid];
    float v[2] = {acc, acc * acc};
    breduce<2>(v, red, 8);
    float m = v[0] / 512.f, va = v[1] / 512.f - m * m, iv = rsqrtf(va + LNEPS);
    h_s[tid] = siluf_((acc - m) * iv * g_po[tid] + b_po[tid]);
    __syncthreads();
    if (tid < 32) {
        float s = b_ps[tid];
        for (int k = 0; k < 512; ++k) s += h_s[k] * W_ps[k * 64 + tid];
        sinit[tid] = s;
    }
}

// ---- t=0 only ----
__global__ __launch_bounds__(256) void k_prior_x(int t, const int* __restrict__ isf, const float* __restrict__ action,
                                                 const float* __restrict__ stoch, const float* __restrict__ sinit,
                                                 const float* __restrict__ dinit, float* __restrict__ deter,
                                                 __hip_bfloat16* __restrict__ dbf, const float* __restrict__ W_pi,
                                                 const float* __restrict__ g_pi, const float* __restrict__ b_pi,
                                                 __hip_bfloat16* __restrict__ xout) {
    int b = blockIdx.x, tid = threadIdx.x;
    __shared__ float a_s[CATPI];
    __shared__ float red[24];
    int first = isf[b * TT + t] > 0;
    if (tid < CATPI) {
        float v;
        if (tid < STOCHN)
            v = (t == 0 || first) ? sinit[tid] : stoch[b * STOCHN + tid];
        else
            v = first ? 0.f : action[((size_t)b * TT + t) * ACTN + (tid - STOCHN)];
        a_s[tid] = v;
    }
    for (int j = tid; j < DETERN; j += 256) {
        float dv = (t == 0 || first) ? dinit[j] : deter[(size_t)b * DETERN + j];
        deter[(size_t)b * DETERN + j] = dv;
        dbf[(size_t)b * DETERN + j] = __float2bfloat16(dv);
    }
    __syncthreads();
    float o[2];
    float vs = 0.f, vq = 0.f;
#pragma unroll
    for (int s = 0; s < 2; ++s) {
        int j = tid + s * 256;
        float acc = 0.f;
        for (int k = 0; k < CATPI; ++k) acc += a_s[k] * W_pi[k * 512 + j];
        o[s] = acc;
        vs += acc;
        vq += acc * acc;
    }
    float v2[2] = {vs, vq};
    breduce<2>(v2, red, 4);
    float m = v2[0] / 512.f, va = v2[1] / 512.f - m * m, iv = rsqrtf(va + LNEPS);
#pragma unroll
    for (int s = 0; s < 2; ++s) {
        int j = tid + s * 256;
        xout[(size_t)b * 512 + j] = __float2bfloat16(siluf_((o[s] - m) * iv * g_pi[j] + b_pi[j]));
    }
}

// ---- LN over gates + GRU update -> deter_n ----
__global__ __launch_bounds__(256) void k_gru_update(int t, const float* __restrict__ gates,
                                                    const float* __restrict__ g_gru, const float* __restrict__ b_gru,
                                                    float* __restrict__ deter, __hip_bfloat16* __restrict__ dbf,
                                                    float* __restrict__ out) {
    int b = blockIdx.x, tid = threadIdx.x;
    __shared__ float red[24];
    const float* grow = gates + (size_t)b * G3N;
    float g[6];
    float s = 0.f, sq = 0.f;
#pragma unroll
    for (int q = 0; q < 6; ++q) {
        g[q] = grow[tid + q * 256];
        s += g[q];
        sq += g[q] * g[q];
    }
    float v[2] = {s, sq};
    breduce<2>(v, red, 4);
    float m = v[0] / 1536.f, va = v[1] / 1536.f - m * m, iv = rsqrtf(va + LNEPS);
    size_t base = ((size_t)b * TT + t) * OUTC + 160;
#pragma unroll
    for (int s2 = 0; s2 < 2; ++s2) {
        int j = tid + s2 * 256;
        float rv = sigmoidf_((g[s2] - m) * iv * g_gru[j] + b_gru[j]);
        float cv = (g[2 + s2] - m) * iv * g_gru[512 + j] + b_gru[512 + j];
        float uv = sigmoidf_((g[4 + s2] - m) * iv * g_gru[1024 + j] + b_gru[1024 + j] + UPDBIAS);
        float cand = siluf_(rv * cv);
        float dp = deter[(size_t)b * DETERN + j];
        float dn = uv * cand + (1.f - uv) * dp;
        deter[(size_t)b * DETERN + j] = dn;
        dbf[(size_t)b * DETERN + j] = __float2bfloat16(dn);
        out[base + j] = dn;
    }
}

// ---- LN+silu on hp/hq, stats GEMMs, outputs, stoch update, fused next-step prior_in ----
__global__ __launch_bounds__(256) void k_stats(int t, const float* __restrict__ hbuf, const float* __restrict__ g_po,
                                               const float* __restrict__ b_po, const float* __restrict__ g_pn,
                                               const float* __restrict__ b_pn, const float* __restrict__ W_ps,
                                               const float* __restrict__ b_ps, const float* __restrict__ W_pt,
                                               const float* __restrict__ b_pt, const int* __restrict__ isf,
                                               const float* __restrict__ action, const float* __restrict__ sinit,
                                               const float* __restrict__ dinit, float* __restrict__ deter,
                                               __hip_bfloat16* __restrict__ dbf, float* __restrict__ stoch,
                                               const float* __restrict__ W_pi, const float* __restrict__ g_pi,
                                               const float* __restrict__ b_pi, __hip_bfloat16* __restrict__ xout,
                                               float* __restrict__ out) {
    int b = blockIdx.x, tid = threadIdx.x;
    __shared__ float hp_s[512], hq_s[512], ps_s[64], qs_s[64], a_s[CATPI], red[24];
    const float* hrow = hbuf + (size_t)b * 1024;
    float p0 = hrow[tid], p1 = hrow[tid + 256];
    float q0 = hrow[512 + tid], q1 = hrow[512 + tid + 256];
    float v[4] = {p0 + p1, p0 * p0 + p1 * p1, q0 + q1, q0 * q0 + q1 * q1};
    breduce<4>(v, red, 4);
    float mp = v[0] / 512.f, vp = v[1] / 512.f - mp * mp, ip = rsqrtf(vp + LNEPS);
    float mq = v[2] / 512.f, vq = v[3] / 512.f - mq * mq, iq = rsqrtf(vq + LNEPS);
    hp_s[tid] = siluf_((p0 - mp) * ip * g_po[tid] + b_po[tid]);
    hp_s[tid + 256] = siluf_((p1 - mp) * ip * g_po[tid + 256] + b_po[tid + 256]);
    hq_s[tid] = siluf_((q0 - mq) * iq * g_pn[tid] + b_pn[tid]);
    hq_s[tid + 256] = siluf_((q1 - mq) * iq * g_pn[tid + 256] + b_pn[tid + 256]);
    __syncthreads();
    if (tid < 64) {
        float acc = b_ps[tid];
        for (int k = 0; k < 512; ++k) acc += hp_s[k] * W_ps[k * 64 + tid];
        ps_s[tid] = acc;
    } else if (tid < 128) {
        int j = tid - 64;
        float acc = b_pt[j];
        for (int k = 0; k < 512; ++k) acc += hq_s[k] * W_pt[k * 64 + j];
        qs_s[j] = acc;
    }
    __syncthreads();
    size_t base = ((size_t)b * TT + t) * OUTC;
    if (tid < 32) {
        float qm = qs_s[tid], pm = ps_s[tid];
        out[base + tid] = qm;
        out[base + 32 + tid] = softplusf_(qs_s[32 + tid]) + MINSTD;
        out[base + 64 + tid] = qm;
        out[base + 96 + tid] = pm;
        out[base + 128 + tid] = softplusf_(ps_s[32 + tid]) + MINSTD;
        stoch[b * STOCHN + tid] = qm;
    }
    if (t + 1 < TT) {
        int first1 = isf[b * TT + t + 1] > 0;
        if (tid < CATPI) {
            float av;
            if (tid < STOCHN)
                av = first1 ? sinit[tid] : qs_s[tid];
            else
                av = first1 ? 0.f : action[((size_t)b * TT + t + 1) * ACTN + (tid - STOCHN)];
            a_s[tid] = av;
        }
        if (first1) {
            for (int j = tid; j < 512; j += 256) {
                deter[(size_t)b * DETERN + j] = dinit[j];
                dbf[(size_t)b * DETERN + j] = __float2bfloat16(dinit[j]);
            }
        }
        __syncthreads();
        float o0 = 0.f, o1 = 0.f;
        for (int k = 0; k < CATPI; ++k) {
            float ak = a_s[k];
            o0 += ak * W_pi[k * 512 + tid];
            o1 += ak * W_pi[k * 512 + tid + 256];
        }
        float v2[2] = {o0 + o1, o0 * o0 + o1 * o1};
        breduce<2>(v2, red, 4);
        float m = v2[0] / 512.f, va = v2[1] / 512.f - m * m, iv = rsqrtf(va + LNEPS);
        xout[(size_t)b * 512 + tid] = __float2bfloat16(siluf_((o0 - m) * iv * g_pi[tid] + b_pi[tid]));
        xout[(size_t)b * 512 + tid + 256] =
            __float2bfloat16(siluf_((o1 - m) * iv * g_pi[tid + 256] + b_pi[tid + 256]));
    }
}

extern "C" void kernel_launch(void* const* d_in, const int* in_sizes, int n_in, void* d_out, int out_size, void* d_ws,
                              size_t ws_size, hipStream_t stream) {
    const float* obs = (const float*)d_in[0];
    const float* action = (const float*)d_in[1];
    const int* is_first = (const int*)d_in[2];
    const float* W_pi = (const float*)d_in[3];
    const float* g_pi = (const float*)d_in[4];
    const float* b_pi = (const float*)d_in[5];
    const float* W_gru = (const float*)d_in[6];
    const float* g_gru = (const float*)d_in[7];
    const float* b_gru = (const float*)d_in[8];
    const float* W_po = (const float*)d_in[9];
    const float* g_po = (const float*)d_in[10];
    const float* b_po = (const float*)d_in[11];
    const float* W_ps = (const float*)d_in[12];
    const float* b_ps = (const float*)d_in[13];
    const float* W_pn = (const float*)d_in[14];
    const float* g_pn = (const float*)d_in[15];
    const float* b_pn = (const float*)d_in[16];
    const float* W_pt = (const float*)d_in[17];
    const float* b_pt = (const float*)d_in[18];
    const float* init_deter = (const float*)d_in[19];
    float* out = (float*)d_out;

    char* p = (char*)d_ws;
    auto alloc = [&](size_t bytes) {
        char* r = p;
        p += (bytes + 255) & ~(size_t)255;
        return r;
    };
    float* deter = (float*)alloc((size_t)BB * 512 * 4);
    float* stoch = (float*)alloc((size_t)BB * 32 * 4);
    float* gates = (float*)alloc((size_t)BB * 1536 * 4);  // aliased as hbuf (disjoint lifetimes)
    float* hbuf = gates;
    float* dinit = (float*)alloc(512 * 4);
    float* sinit = (float*)alloc(32 * 4);
    __hip_bfloat16* xbf = (__hip_bfloat16*)alloc((size_t)BB * 512 * 2);
    __hip_bfloat16* dbf = (__hip_bfloat16*)alloc((size_t)BB * 512 * 2);
    __hip_bfloat16* obsbf = (__hip_bfloat16*)alloc((size_t)BB * TT * OBSN * 2);
    __hip_bfloat16* WgT = (__hip_bfloat16*)alloc((size_t)1536 * 1024 * 2);
    __hip_bfloat16* WpoT = (__hip_bfloat16*)alloc((size_t)512 * 512 * 2);
    __hip_bfloat16* WpnT = (__hip_bfloat16*)alloc((size_t)512 * 576 * 2);

    // one-time conversions
    k_transpose_bf<<<(1024 / 32) * (1536 / 32), 256, 0, stream>>>(W_gru, WgT, 1024, 1536);
    k_transpose_bf<<<(512 / 32) * (512 / 32), 256, 0, stream>>>(W_po, WpoT, 512, 512);
    k_transpose_bf<<<(576 / 32) * (512 / 32), 256, 0, stream>>>(W_pn, WpnT, 576, 512);
    k_cvt_bf<<<2048, 256, 0, stream>>>(obs, obsbf, BB * TT * OBSN);
    k_init<<<1, 512, 0, stream>>>(init_deter, W_po, g_po, b_po, W_ps, b_ps, dinit, sinit);
    k_prior_x<<<BB, 256, 0, stream>>>(0, is_first, action, stoch, sinit, dinit, deter, dbf, W_pi, g_pi, b_pi, xbf);
    for (int t = 0; t < TT; ++t) {
        k_gemm_gru<<<16 * 12, 256, 0, stream>>>(xbf, dbf, WgT, gates);
        k_gru_update<<<BB, 256, 0, stream>>>(t, gates, g_gru, b_gru, deter, dbf, out);
        k_gemm_h<<<16 * 8, 256, 0, stream>>>(t, dbf, obsbf, WpoT, WpnT, hbuf);
        k_stats<<<BB, 256, 0, stream>>>(t, hbuf, g_po, b_po, g_pn, b_pn, W_ps, b_ps, W_pt, b_pt, is_first, action,
                                        sinit, dinit, deter, dbf, stoch, W_pi, g_pi, b_pi, xbf, out);
    }
}